// Round 8
// baseline (121.223 us; speedup 1.0000x reference)
//
#include <hip/hip_runtime.h>
#include <math.h>

#define BB 64
#define WW 128
#define FF 64
#define HH 4
#define OW 128

// ---------------------------------------------------------------------------
// Kernel 1: projections, 2-batch-wide LDS GEMM, 8x8 register tile.
// Grid 512 = bp(32 pairs) x rt(16): rows rm0..rm0+63 of [Wsrc|Wdst] (512 each).
// Block 128 thr (2 waves). LDS 51.5 KB -> 2 blocks/CU.
// Per k: 2 b128 x-reads (contiguous spread) + 2 b128 W-reads (4-addr bcast)
// feed 64 FMAs -> 4 ds per 64 VALU (2x better than r7).
// Output: fs/fd [B][H][i][d].
// ---------------------------------------------------------------------------
__global__ __launch_bounds__(128) void gat_proj(
    const float* __restrict__ x,     // [B][128 k][64 f]
    const float* __restrict__ Wsrc,  // [512][128]
    const float* __restrict__ bsrc,
    const float* __restrict__ Wdst,
    const float* __restrict__ bdst,
    float* __restrict__ fs,          // [B][H][64][128]
    float* __restrict__ fd)
{
    __shared__ float x2l[64 * 132];      // 33.8 KB [k_half][f2=bb*64+f]
    __shared__ float wlt[64 * 68];       // 17.4 KB [k_half][r] transposed
    __shared__ float bl[64];

    const int bp = blockIdx.x >> 4;
    const int rt = blockIdx.x & 15;
    const bool is_src = rt < 8;
    const int rm0 = (rt & 7) * 64;
    const int b0  = bp * 2;

    const float* Wm = is_src ? Wsrc : Wdst;
    const float* bm = is_src ? bsrc : bdst;

    const int t  = threadIdx.x;
    const int tx = t & 15;               // i-quad (both batches)
    const int ty = t >> 4;               // 0..7 -> r0 = ty*8

    float acc[8][8] = {};                // [rr(d)][e(bb0:0-3, bb1:4-7)]

    for (int kp = 0; kp < 2; ++kp) {
        // ---- stage x2: 2048 f4 (16/thread) ----
        #pragma unroll
        for (int p = 0; p < 16; ++p) {
            int idx = p * 128 + t;
            int k = idx >> 5, fq = idx & 31;
            int bb = fq >> 4, fi = fq & 15;
            float4 v = *(const float4*)(x + (((size_t)(b0 + bb) * WW) + kp * 64 + k) * FF + fi * 4);
            *(float4*)&x2l[k * 132 + bb * 64 + fi * 4] = v;
        }
        // ---- stage W transposed: 1024 f4 (8/thread) ----
        #pragma unroll
        for (int p = 0; p < 8; ++p) {
            int idx = p * 128 + t;
            int r = idx >> 4, kq = idx & 15;
            float4 v = *(const float4*)(Wm + (size_t)(rm0 + r) * WW + kp * 64 + kq * 4);
            wlt[(kq * 4 + 0) * 68 + r] = v.x;
            wlt[(kq * 4 + 1) * 68 + r] = v.y;
            wlt[(kq * 4 + 2) * 68 + r] = v.z;
            wlt[(kq * 4 + 3) * 68 + r] = v.w;
        }
        if (kp == 0 && t < 64) bl[t] = bm[rm0 + t];
        __syncthreads();

        // ---- compute 64 k, fully register-resident ----
        #pragma unroll 8
        for (int k = 0; k < 64; ++k) {
            const float* xa = &x2l[k * 132 + tx * 4];
            float4 xv0 = *(const float4*)xa;            // bb=0, contiguous spread
            float4 xv1 = *(const float4*)(xa + 64);     // bb=1
            const float* wa = &wlt[k * 68 + ty * 8];
            float4 wv0 = *(const float4*)wa;            // 4-addr bcast
            float4 wv1 = *(const float4*)(wa + 4);
            const float* xf0 = (const float*)&xv0;
            const float* xf1 = (const float*)&xv1;
            const float* wf0 = (const float*)&wv0;
            const float* wf1 = (const float*)&wv1;
            #pragma unroll
            for (int rr = 0; rr < 4; ++rr) {
                const float w0 = wf0[rr], w1 = wf1[rr];
                #pragma unroll
                for (int e = 0; e < 4; ++e) {
                    acc[rr][e]         = fmaf(w0, xf0[e], acc[rr][e]);
                    acc[rr][4 + e]     = fmaf(w0, xf1[e], acc[rr][4 + e]);
                    acc[4 + rr][e]     = fmaf(w1, xf0[e], acc[4 + rr][e]);
                    acc[4 + rr][4 + e] = fmaf(w1, xf1[e], acc[4 + rr][4 + e]);
                }
            }
        }
        __syncthreads();
    }

    // ---- epilogue: bias + store [b][h][i][d], f4 over d ----
    const int h  = rm0 >> 7;
    const int d0 = (rm0 & 127) + ty * 8;
    float* base = (is_src ? fs : fd);
    #pragma unroll
    for (int bb = 0; bb < 2; ++bb) {
        #pragma unroll
        for (int e = 0; e < 4; ++e) {
            const int i = tx * 4 + e;
            const int col = bb * 4 + e;
            float* dst = base + ((((size_t)(b0 + bb) * HH + h) * FF) + i) * OW + d0;
            #pragma unroll
            for (int q = 0; q < 2; ++q) {
                float4 o;
                o.x = acc[q * 4 + 0][col] + bl[ty * 8 + q * 4 + 0];
                o.y = acc[q * 4 + 1][col] + bl[ty * 8 + q * 4 + 1];
                o.z = acc[q * 4 + 2][col] + bl[ty * 8 + q * 4 + 2];
                o.w = acc[q * 4 + 3][col] + bl[ty * 8 + q * 4 + 3];
                *(float4*)&dst[q * 4] = o;
            }
        }
    }
}

// ---------------------------------------------------------------------------
// Kernel 2: scores + edge-softmax + aggregation per (b,h). Grid 256 = 1/CU.
// Block 256 thr. LDS ~90 KB. fd staged TRANSPOSED [d][j] so phase-1 fd reads
// are contiguous-256B b128; fs reads are 4-addr bcast. 4i x 4j score tile
// (9 ds per 128 VALU ops); phase 3 4j x 8d (3 ds per 32 FMAs).
// score = cs_i + cd_j + sum_d 0.4a|fs+fd|; head-mean folded into 1/l.
// ---------------------------------------------------------------------------
__global__ __launch_bounds__(256) void gat_attn(
    const float* __restrict__ fs,    // [B][H][64 i][128 d]
    const float* __restrict__ fd,    // [B][H][64 j][128 d]
    const float* __restrict__ attn,  // [H][128]
    float* __restrict__ ws2)         // [B][H][64 j][128 d]
{
    __shared__ float fsl[FF * 132];      // 33.8 KB [i][d]
    __shared__ float fdt[OW * 68];       // 34.8 KB [d][j] transposed
    __shared__ float St[FF * 68];        // 17.4 KB [i][j]
    __shared__ float A6[OW], B4[OW];
    __shared__ float cs[FF], cd[FF];
    __shared__ float redm[4][FF];
    __shared__ float reds[4][FF];
    __shared__ float invl[FF];

    const int h = blockIdx.x & 3;
    const int b = blockIdx.x >> 2;
    const size_t bh = (size_t)b * HH + h;

    const int t    = threadIdx.x;
    const int wv   = t >> 6;
    const int lane = t & 63;

    // ---- stage fsl (coalesced), fdt (transposed), attn coefs ----
    {
        const float4* s = (const float4*)(fs + bh * (FF * OW));
        #pragma unroll
        for (int p = 0; p < 8; ++p) {
            int idx = p * 256 + t;
            int i = idx >> 5, kq = idx & 31;
            *(float4*)&fsl[i * 132 + kq * 4] = s[idx];
        }
        const float* fdg = fd + bh * (FF * OW);
        #pragma unroll
        for (int p = 0; p < 8; ++p) {
            int dq = p * 4 + wv;                 // wave-uniform
            int j  = lane;
            float4 v = *(const float4*)(fdg + (size_t)j * OW + dq * 4);
            fdt[(dq * 4 + 0) * 68 + j] = v.x;    // consecutive j: conflict-free
            fdt[(dq * 4 + 1) * 68 + j] = v.y;
            fdt[(dq * 4 + 2) * 68 + j] = v.z;
            fdt[(dq * 4 + 3) * 68 + j] = v.w;
        }
        if (t < 128) {
            float a = attn[h * OW + t];
            A6[t] = 0.6f * a;
            B4[t] = 0.4f * a;
        }
    }
    __syncthreads();

    // ---- cs_i (wave 0) and cd_j (wave 1) ----
    if (wv == 0) {
        float s = 0.0f;
        #pragma unroll 8
        for (int c = 0; c < 32; ++c) {
            float4 fv = *(const float4*)&fsl[lane * 132 + c * 4];
            float4 av = *(const float4*)&A6[c * 4];
            s = fmaf(fv.x, av.x, fmaf(fv.y, av.y, fmaf(fv.z, av.z, fmaf(fv.w, av.w, s))));
        }
        cs[lane] = s;
    } else if (wv == 1) {
        float s = 0.0f;
        #pragma unroll 16
        for (int d = 0; d < OW; ++d)
            s = fmaf(fdt[d * 68 + lane], A6[d], s);
        cd[lane] = s;
    }
    __syncthreads();

    // ---- phase 1: scores, 4i x 4j per thread ----
    {
        const int ig = t >> 4, jg = t & 15;
        const int i0 = ig * 4, j0 = jg * 4;
        float sc[4][4] = {};
        #pragma unroll 2
        for (int c = 0; c < 32; ++c) {
            const int d0 = c * 4;
            float4 fsv[4], fdv[4];
            #pragma unroll
            for (int m = 0; m < 4; ++m)
                fsv[m] = *(const float4*)&fsl[(i0 + m) * 132 + d0];  // 4-addr bcast
            #pragma unroll
            for (int e = 0; e < 4; ++e)
                fdv[e] = *(const float4*)&fdt[(d0 + e) * 68 + j0];   // contig 256B
            float4 b4 = *(const float4*)&B4[d0];
            const float* bf = (const float*)&b4;
            #pragma unroll
            for (int m = 0; m < 4; ++m) {
                const float* fm = (const float*)&fsv[m];
                #pragma unroll
                for (int e = 0; e < 4; ++e) {
                    const float* fe = (const float*)&fdv[e];
                    const float fv = fm[e], be = bf[e];
                    sc[m][0] = fmaf(be, fabsf(fv + fe[0]), sc[m][0]);
                    sc[m][1] = fmaf(be, fabsf(fv + fe[1]), sc[m][1]);
                    sc[m][2] = fmaf(be, fabsf(fv + fe[2]), sc[m][2]);
                    sc[m][3] = fmaf(be, fabsf(fv + fe[3]), sc[m][3]);
                }
            }
        }
        float4 cdv = *(const float4*)&cd[j0];
        #pragma unroll
        for (int m = 0; m < 4; ++m) {
            const float csm = cs[i0 + m];
            float4 o;
            o.x = sc[m][0] + csm + cdv.x;
            o.y = sc[m][1] + csm + cdv.y;
            o.z = sc[m][2] + csm + cdv.z;
            o.w = sc[m][3] + csm + cdv.w;
            *(float4*)&St[(i0 + m) * 68 + j0] = o;
        }
    }
    __syncthreads();

    // ---- phase 2: softmax over i per column j (4 strips of 16 i) ----
    {
        const int st = t >> 6, j = t & 63;
        const int i0 = st * 16;
        float m = St[i0 * 68 + j];
        #pragma unroll
        for (int ii = 1; ii < 16; ++ii) m = fmaxf(m, St[(i0 + ii) * 68 + j]);
        redm[st][j] = m;
    }
    __syncthreads();
    {
        const int st = t >> 6, j = t & 63;
        const int i0 = st * 16;
        float mj = fmaxf(fmaxf(redm[0][j], redm[1][j]), fmaxf(redm[2][j], redm[3][j]));
        float ps = 0.0f;
        #pragma unroll
        for (int ii = 0; ii < 16; ++ii) {
            float e = __expf(St[(i0 + ii) * 68 + j] - mj);
            St[(i0 + ii) * 68 + j] = e;
            ps += e;
        }
        reds[st][j] = ps;
    }
    __syncthreads();
    if (t < 64)
        invl[t] = 0.25f / (reds[0][t] + reds[1][t] + reds[2][t] + reds[3][t]);
    __syncthreads();

    // ---- phase 3: aggregation, 4j x 8d per thread ----
    {
        const int jg = t & 15, dg = t >> 4;
        const int j0 = jg * 4, d0 = dg * 8;
        float ag[4][8] = {};
        #pragma unroll 2
        for (int i = 0; i < FF; ++i) {
            float4 pv = *(const float4*)&St[i * 68 + j0];       // contig 256B
            float4 f0 = *(const float4*)&fsl[i * 132 + d0];     // 4-addr bcast
            float4 f1 = *(const float4*)&fsl[i * 132 + d0 + 4];
            const float* pf = (const float*)&pv;
            const float* fa = (const float*)&f0;
            const float* fb = (const float*)&f1;
            #pragma unroll
            for (int n = 0; n < 4; ++n) {
                const float p = pf[n];
                #pragma unroll
                for (int e = 0; e < 4; ++e) {
                    ag[n][e]     = fmaf(p, fa[e], ag[n][e]);
                    ag[n][4 + e] = fmaf(p, fb[e], ag[n][4 + e]);
                }
            }
        }
        float* wout = ws2 + (bh * FF) * OW;
        #pragma unroll
        for (int n = 0; n < 4; ++n) {
            const float iv = invl[j0 + n];
            #pragma unroll
            for (int q = 0; q < 2; ++q) {
                float4 o;
                o.x = ag[n][q * 4 + 0] * iv;
                o.y = ag[n][q * 4 + 1] * iv;
                o.z = ag[n][q * 4 + 2] * iv;
                o.w = ag[n][q * 4 + 3] * iv;
                *(float4*)&wout[(size_t)(j0 + n) * OW + d0 + q * 4] = o;
            }
        }
    }
}

// ---------------------------------------------------------------------------
// Kernel 3: head-sum + transpose -> out[b][d][f]. Grid 256 = (b, jg of 16).
// ---------------------------------------------------------------------------
__global__ __launch_bounds__(256) void gat_reduce(
    const float* __restrict__ ws2,   // [B][H][64 j][128 d]
    float* __restrict__ out)         // [B][128 d][64 f]
{
    __shared__ float tl[16][132];
    const int b  = blockIdx.x >> 2;
    const int jg = blockIdx.x & 3;
    const int t  = threadIdx.x;

    const float* base = ws2 + ((size_t)b * HH * FF + jg * 16) * OW;
    #pragma unroll
    for (int p = 0; p < 2; ++p) {
        int idx = p * 256 + t;
        int j = idx >> 5, q = idx & 31;
        const float* src = base + (size_t)j * OW + q * 4;
        float4 s0 = *(const float4*)(src);
        float4 s1 = *(const float4*)(src + (size_t)FF * OW);
        float4 s2 = *(const float4*)(src + (size_t)2 * FF * OW);
        float4 s3 = *(const float4*)(src + (size_t)3 * FF * OW);
        float4 o;
        o.x = s0.x + s1.x + s2.x + s3.x;
        o.y = s0.y + s1.y + s2.y + s3.y;
        o.z = s0.z + s1.z + s2.z + s3.z;
        o.w = s0.w + s1.w + s2.w + s3.w;
        *(float4*)&tl[j][q * 4] = o;
    }
    __syncthreads();
    #pragma unroll
    for (int it = 0; it < 8; ++it) {
        int idx = it * 256 + t;
        int j = idx & 15, d = idx >> 4;
        out[((size_t)b * OW + d) * FF + jg * 16 + j] = tl[j][d];
    }
}

// ---------------------------------------------------------------------------
extern "C" void kernel_launch(void* const* d_in, const int* in_sizes, int n_in,
                              void* d_out, int out_size, void* d_ws, size_t ws_size,
                              hipStream_t stream) {
    const float* x    = (const float*)d_in[0];
    const float* Wsrc = (const float*)d_in[1];
    const float* bsrc = (const float*)d_in[2];
    const float* Wdst = (const float*)d_in[3];
    const float* bdst = (const float*)d_in[4];
    const float* attn = (const float*)d_in[5];
    float* out = (float*)d_out;

    const size_t SL = (size_t)BB * HH * FF * OW;      // 2M floats = 8 MB
    float* fs  = (float*)d_ws;
    float* fd  = fs + SL;
    float* ws2 = fd + SL;

    gat_proj  <<<32 * 16, 128, 0, stream>>>(x, Wsrc, bsrc, Wdst, bdst, fs, fd);
    gat_attn  <<<BB * HH, 256, 0, stream>>>(fs, fd, attn, ws2);
    gat_reduce<<<BB * 4,  256, 0, stream>>>(ws2, out);
}